// Round 4
// baseline (2359.576 us; speedup 1.0000x reference)
//
#include <hip/hip_runtime.h>
#include <hip/hip_bf16.h>
#include <hip/hip_fp16.h>

typedef __attribute__((ext_vector_type(8))) short short8;
typedef __attribute__((ext_vector_type(4))) float f32x4;

__device__ __forceinline__ unsigned short dev_f2bf(float f) {
  __hip_bfloat16 b = __float2bfloat16(f);
  union { __hip_bfloat16 b; unsigned short u; } c; c.b = b; return c.u;
}
__device__ __forceinline__ float dev_bf2f(unsigned short u) {
  union { unsigned int i; float f; } c; c.i = ((unsigned int)u) << 16; return c.f;
}
__device__ __forceinline__ unsigned short dev_f2h(float f) {
  __half h = __float2half(f);
  union { __half h; unsigned short u; } c; c.h = h; return c.u;
}
__device__ __forceinline__ float dev_h2f(unsigned short u) {
  union { unsigned short u; __half h; } c; c.u = u; return __half2float(c.h);
}

// async global->LDS, 16B per lane; dest = lds_base(wave-uniform) + lane*16
__device__ __forceinline__ void gload_lds16(const unsigned short* g, unsigned short* l) {
  __builtin_amdgcn_global_load_lds(
      (const __attribute__((address_space(1))) void*)(const void*)g,
      (__attribute__((address_space(3))) void*)(void*)l, 16, 0, 0);
}

struct GemmP {
  const unsigned short* A;   // bf16 bits
  const unsigned short* B;   // bf16 bits
  void* C;
  const float* biasN;        // bias by output col, may be null
  const float* biasM;        // bias by output row, may be null
  long long aHi, aLo, bHi, bLo, cHi, cLo;  // per-z base: (z>>4)*Hi + (z&15)*Lo
  int K;
  int sAm;                   // A row stride (k stride == 1)
  int sBn;                   // B row stride (k stride == 1)
  int sCm, sCn;
  float scale;
  int relu;
  int cdtype;                // 0=bf16, 1=f32, 2=f16, 3=f32 +=
};

// General NT GEMM: C[z,m,n] = scale * sum_k A[m,k]*B[n,k] + biases
// global_load_lds(16B) staging into linear LDS [rows][64]; mfma 16x16x32 bf16.
template<int BM, int BN, int WM, int WN>
__global__ __launch_bounds__(256, 2) void gemm_nt(GemmP p) {
  constexpr int BK = 64;
  constexpr int TM = BM / WM, TN = BN / WN;
  constexpr int FM = TM / 16, FN = TN / 16;
  __shared__ __align__(16) unsigned short As[BM * BK];
  __shared__ __align__(16) unsigned short Bs[BN * BK];

  const int tid = threadIdx.x;
  const int lane = tid & 63;
  const int wid = tid >> 6;
  const int wm = wid / WN, wn = wid % WN;
  const int m0 = blockIdx.x * BM;
  const int n0 = blockIdx.y * BN;
  const int z = blockIdx.z;
  const int zq = z >> 4, zr = z & 15;
  const unsigned short* Ag = p.A + (long long)zq * p.aHi + (long long)zr * p.aLo;
  const unsigned short* Bg = p.B + (long long)zq * p.bHi + (long long)zr * p.bLo;

  const int srow = tid >> 3;        // 0..31
  const int scol = (tid & 7) * 8;   // 0..56
  constexpr int AC = BM / 32, BC = BN / 32;

  f32x4 acc[FM][FN];
#pragma unroll
  for (int i = 0; i < FM; i++)
#pragma unroll
    for (int j = 0; j < FN; j++)
      acc[i][j] = f32x4{0.f, 0.f, 0.f, 0.f};

  for (int k0 = 0; k0 < p.K; k0 += BK) {
#pragma unroll
    for (int i = 0; i < AC; i++)
      gload_lds16(Ag + (long long)(m0 + i * 32 + srow) * p.sAm + (k0 + scol),
                  &As[i * 2048 + wid * 512]);
#pragma unroll
    for (int i = 0; i < BC; i++)
      gload_lds16(Bg + (long long)(n0 + i * 32 + srow) * p.sBn + (k0 + scol),
                  &Bs[i * 2048 + wid * 512]);
    __syncthreads();
#pragma unroll
    for (int ks = 0; ks < 2; ks++) {
      const int ko = ks * 32 + (lane >> 4) * 8;
      short8 a[FM], b[FN];
#pragma unroll
      for (int i = 0; i < FM; i++)
        a[i] = *(const short8*)&As[(wm * TM + i * 16 + (lane & 15)) * BK + ko];
#pragma unroll
      for (int j = 0; j < FN; j++)
        b[j] = *(const short8*)&Bs[(wn * TN + j * 16 + (lane & 15)) * BK + ko];
#pragma unroll
      for (int i = 0; i < FM; i++)
#pragma unroll
        for (int j = 0; j < FN; j++)
          acc[i][j] = __builtin_amdgcn_mfma_f32_16x16x32_bf16(a[i], b[j], acc[i][j], 0, 0, 0);
    }
    __syncthreads();
  }

  const long long zc_ = (long long)zq * p.cHi + (long long)zr * p.cLo;
#pragma unroll
  for (int i = 0; i < FM; i++) {
#pragma unroll
    for (int j = 0; j < FN; j++) {
      const int col = n0 + wn * TN + j * 16 + (lane & 15);
      float bn = p.biasN ? p.biasN[col] : 0.f;
#pragma unroll
      for (int r = 0; r < 4; r++) {
        const int row = m0 + wm * TM + i * 16 + ((lane >> 4) << 2) + r;
        float v = acc[i][j][r] * p.scale + bn;
        if (p.biasM) v += p.biasM[row];
        if (p.relu) v = fmaxf(v, 0.f);
        const long long addr = zc_ + (long long)row * p.sCm + (long long)col * p.sCn;
        if (p.cdtype == 0)      ((unsigned short*)p.C)[addr] = dev_f2bf(v);
        else if (p.cdtype == 1) ((float*)p.C)[addr] = v;
        else if (p.cdtype == 2) ((unsigned short*)p.C)[addr] = dev_f2h(v);
        else                    ((float*)p.C)[addr] += v;
      }
    }
  }
}

// 64x64 tiled transpose: in [b][4096][1024] -> out [b][1024][4096] (bf16)
__global__ __launch_bounds__(256) void transpose_kernel(const unsigned short* __restrict__ in,
                                                        unsigned short* __restrict__ out) {
  __shared__ unsigned short t[64][72];
  const int b = blockIdx.z;
  const int n0 = blockIdx.x * 64, c0 = blockIdx.y * 64;
  const int r = threadIdx.x >> 2;          // 0..63
  const int cc = (threadIdx.x & 3) * 16;   // 0,16,32,48
  const unsigned short* ip = in + (size_t)b * 4194304 + (size_t)n0 * 1024 + c0;
  *(short8*)&t[r][cc]     = *(const short8*)(ip + (size_t)r * 1024 + cc);
  *(short8*)&t[r][cc + 8] = *(const short8*)(ip + (size_t)r * 1024 + cc + 8);
  __syncthreads();
  unsigned short* op = out + (size_t)b * 4194304 + (size_t)c0 * 4096 + n0;
  short8 w0, w1;
#pragma unroll
  for (int j = 0; j < 8; j++) {
    w0[j] = (short)t[cc + j][r];
    w1[j] = (short)t[cc + 8 + j][r];
  }
  *(short8*)(op + (size_t)r * 4096 + cc)     = w0;
  *(short8*)(op + (size_t)r * 4096 + cc + 8) = w1;
}

// f32 -> bf16 (optionally also copy raw f32), x4 vectorized, grid-stride
__global__ void cvt_kernel(const float* __restrict__ src, unsigned short* __restrict__ dst,
                           float* __restrict__ dstf, long long n4) {
  long long i = (long long)blockIdx.x * blockDim.x + threadIdx.x;
  const long long stride = (long long)gridDim.x * blockDim.x;
  for (; i < n4; i += stride) {
    float4 v = ((const float4*)src)[i];
    ushort4 u;
    u.x = dev_f2bf(v.x); u.y = dev_f2bf(v.y); u.z = dev_f2bf(v.z); u.w = dev_f2bf(v.w);
    ((ushort4*)dst)[i] = u;
    if (dstf) ((float4*)dstf)[i] = v;
  }
}

// rows of 256: f16 scores in, bf16 probs out, in place; one wave per row
__global__ __launch_bounds__(256) void softmax_kernel(unsigned short* __restrict__ S) {
  const long long row = (long long)blockIdx.x * 4 + (threadIdx.x >> 6);
  const int lane = threadIdx.x & 63;
  unsigned short* rp = S + row * 256;
  ushort4 u = *(const ushort4*)(rp + lane * 4);
  float x0 = dev_h2f(u.x), x1 = dev_h2f(u.y), x2 = dev_h2f(u.z), x3 = dev_h2f(u.w);
  float m = fmaxf(fmaxf(x0, x1), fmaxf(x2, x3));
#pragma unroll
  for (int off = 32; off > 0; off >>= 1) m = fmaxf(m, __shfl_xor(m, off));
  float e0 = __expf(x0 - m), e1 = __expf(x1 - m), e2 = __expf(x2 - m), e3 = __expf(x3 - m);
  float s = e0 + e1 + e2 + e3;
#pragma unroll
  for (int off = 32; off > 0; off >>= 1) s += __shfl_xor(s, off);
  const float inv = 1.f / s;
  ushort4 o;
  o.x = dev_f2bf(e0 * inv); o.y = dev_f2bf(e1 * inv);
  o.z = dev_f2bf(e2 * inv); o.w = dev_f2bf(e3 * inv);
  *(ushort4*)(rp + lane * 4) = o;
}

// LN over rows of 1024 of xf (f32, holds x+y). Writes LN result to xf and bf16 to xd.
__global__ __launch_bounds__(256) void add_ln_kernel(float* __restrict__ xf,
    unsigned short* __restrict__ xd,
    const float* __restrict__ g, const float* __restrict__ b) {
  const long long row = blockIdx.x;
  const int tid = threadIdx.x;
  float4 t = ((const float4*)(xf + row * 1024))[tid];
  float s = t.x + t.y + t.z + t.w;
  float ss = t.x * t.x + t.y * t.y + t.z * t.z + t.w * t.w;
#pragma unroll
  for (int off = 32; off > 0; off >>= 1) { s += __shfl_xor(s, off); ss += __shfl_xor(ss, off); }
  __shared__ float sm[8];
  const int wid = tid >> 6, lane = tid & 63;
  if (lane == 0) { sm[wid] = s; sm[4 + wid] = ss; }
  __syncthreads();
  s = sm[0] + sm[1] + sm[2] + sm[3];
  ss = sm[4] + sm[5] + sm[6] + sm[7];
  const float mean = s * (1.f / 1024.f);
  const float var = ss * (1.f / 1024.f) - mean * mean;
  const float rs = rsqrtf(var + 1e-5f);
  float4 gv = ((const float4*)g)[tid];
  float4 bv = ((const float4*)b)[tid];
  float4 o = {(t.x - mean) * rs * gv.x + bv.x, (t.y - mean) * rs * gv.y + bv.y,
              (t.z - mean) * rs * gv.z + bv.z, (t.w - mean) * rs * gv.w + bv.w};
  ((float4*)(xf + row * 1024))[tid] = o;
  ushort4 ob;
  ob.x = dev_f2bf(o.x); ob.y = dev_f2bf(o.y); ob.z = dev_f2bf(o.z); ob.w = dev_f2bf(o.w);
  ((ushort4*)(xd + row * 1024))[tid] = ob;
}

// canary: unambiguous "workspace too small" signal (absmax ~ 100+max|ref|)
__global__ void fill_canary_kernel(float* p, long long n) {
  long long i = (long long)blockIdx.x * blockDim.x + threadIdx.x;
  const long long stride = (long long)gridDim.x * blockDim.x;
  for (; i < n; i += stride) p[i] = 100.0f;
}

extern "C" void kernel_launch(void* const* d_in, const int* in_sizes, int n_in,
                              void* d_out, int out_size, void* d_ws, size_t ws_size,
                              hipStream_t stream) {
  const float* x_in  = (const float*)d_in[0];
  const float* E_w   = (const float*)d_in[1];
  const float* E_b   = (const float*)d_in[2];
  const float* Wq    = (const float*)d_in[3];
  const float* Wk    = (const float*)d_in[4];
  const float* Wv    = (const float*)d_in[5];
  const float* wo_w  = (const float*)d_in[6];
  const float* wo_b  = (const float*)d_in[7];
  const float* ln1_g = (const float*)d_in[8];
  const float* ln1_b = (const float*)d_in[9];
  const float* ff_w1 = (const float*)d_in[10];
  const float* ff_b1 = (const float*)d_in[11];
  const float* ff_w2 = (const float*)d_in[12];
  const float* ff_b2 = (const float*)d_in[13];
  const float* ln2_g = (const float*)d_in[14];
  const float* ln2_b = (const float*)d_in[15];

  float* xf = (float*)d_out;   // f32 residual master lives in d_out

  char* ws = (char*)d_ws;
  size_t off = 0;
  auto alloc = [&](size_t bytes) -> char* {
    char* p = ws + off;
    off = (off + bytes + 255) & ~(size_t)255;
    return p;
  };
  unsigned short* E16 = (unsigned short*)alloc(1048576ULL * 2);  // E_w bf16 [256,4096]
  unsigned short* WqL = (unsigned short*)alloc(1048576ULL * 2);  // per-layer slices
  unsigned short* WkL = (unsigned short*)alloc(1048576ULL * 2);
  unsigned short* WvL = (unsigned short*)alloc(1048576ULL * 2);
  unsigned short* WoL = (unsigned short*)alloc(1048576ULL * 2);
  unsigned short* F1L = (unsigned short*)alloc(4194304ULL * 2);
  unsigned short* F2L = (unsigned short*)alloc(4194304ULL * 2);
  unsigned short* xE  = (unsigned short*)alloc(1048576ULL * 2);  // [b][256][1024]
  unsigned short* EK  = (unsigned short*)alloc(1048576ULL * 2);  // [z][256][64]
  unsigned short* EVt = (unsigned short*)alloc(1048576ULL * 2);  // [z][64][256]
  unsigned short* Qb  = (unsigned short*)alloc(4194304ULL * 2);  // per-batch Q / cat
  unsigned short* xd  = (unsigned short*)alloc(16777216ULL * 2); // bf16 working x
  unsigned short* xT  = (unsigned short*)alloc(16777216ULL * 2); // bf16 x^T [b][1024][4096]

  size_t rem = (ws_size > off) ? ws_size - off : 0;
  size_t Rbytes = rem > 512 ? rem - 512 : 0;
  if (Rbytes > 134217728ULL) Rbytes = 134217728ULL;
  int zc = 16;
  while (zc > 1 && (size_t)zc * 2097152ULL > Rbytes) zc >>= 1;
  int rowc = 16384;
  while (rowc > 128 && (size_t)rowc * 8192ULL > Rbytes) rowc >>= 1;
  if ((size_t)zc * 2097152ULL > Rbytes || (size_t)rowc * 8192ULL > Rbytes) {
    fill_canary_kernel<<<2048, 256, 0, stream>>>(xf, (long long)out_size);
    return;
  }
  char* R = alloc(Rbytes);

  auto cvt = [&](const float* s, unsigned short* d, float* df, long long n) {
    long long n4 = n / 4;
    int grid = (int)((n4 + 255) / 256);
    if (grid > 4096) grid = 4096;
    cvt_kernel<<<grid, 256, 0, stream>>>(s, d, df, n4);
  };

  cvt(x_in, xd, xf, 16777216);     // x: bf16 into ws, f32 master into d_out
  cvt(E_w, E16, nullptr, 1048576);

  for (int l = 0; l < 2; l++) {
    cvt(Wq + (size_t)l * 1048576, WqL, nullptr, 1048576);
    cvt(Wk + (size_t)l * 1048576, WkL, nullptr, 1048576);
    cvt(Wv + (size_t)l * 1048576, WvL, nullptr, 1048576);
    cvt(wo_w + (size_t)l * 1048576, WoL, nullptr, 1048576);
    cvt(ff_w1 + (size_t)l * 4194304, F1L, nullptr, 4194304);
    cvt(ff_w2 + (size_t)l * 4194304, F2L, nullptr, 4194304);

    // ---- xT[b][c][n] = x[b][n][c]
    transpose_kernel<<<dim3(64, 16, 4), 256, 0, stream>>>(xd, xT);

    // ---- xE[b][k][c] = sum_n E_w[k,n] * xT[b][c][n]   (pure NT, z = b)
    GemmP pe{};
    pe.A = E16; pe.sAm = 4096; pe.K = 4096;
    pe.B = xT; pe.sBn = 4096; pe.bLo = 4194304;
    pe.C = xE; pe.cLo = 262144; pe.sCm = 1024; pe.sCn = 1;
    pe.scale = 1.f; pe.cdtype = 0;
    gemm_nt<64,128,2,2><<<dim3(4, 8, 4), 256, 0, stream>>>(pe);

    // ---- EK[z][k][d] = xE[b] @ Wk[h]^T + E_b[k]   (z = b*16+h)
    GemmP pk{};
    pk.A = xE; pk.sAm = 1024; pk.K = 1024; pk.aHi = 262144; pk.aLo = 0;
    pk.B = WkL; pk.sBn = 1024; pk.bHi = 0; pk.bLo = 65536;
    pk.C = EK; pk.cHi = 262144; pk.cLo = 16384; pk.sCm = 64; pk.sCn = 1;
    pk.biasM = E_b; pk.scale = 1.f; pk.cdtype = 0;
    gemm_nt<64,64,2,2><<<dim3(4, 1, 64), 256, 0, stream>>>(pk);
    // ---- EVt[z][d][k] = (xE[b] @ Wv[h]^T + E_b[k])^T
    GemmP pv2 = pk;
    pv2.B = WvL; pv2.C = EVt; pv2.sCm = 1; pv2.sCn = 256;
    gemm_nt<64,64,2,2><<<dim3(4, 1, 64), 256, 0, stream>>>(pv2);

    for (int b = 0; b < 4; b++) {
      // ---- Q[b] = x[b] @ Wq^T : [4096,1024]
      GemmP pq{};
      pq.A = xd + (size_t)b * 4194304; pq.sAm = 1024; pq.K = 1024;
      pq.B = WqL; pq.sBn = 1024;
      pq.C = Qb; pq.sCm = 1024; pq.sCn = 1;
      pq.scale = 1.f; pq.cdtype = 0;
      gemm_nt<128,128,2,2><<<dim3(32, 8, 1), 256, 0, stream>>>(pq);

      for (int h0 = 0; h0 < 16; h0 += zc) {
        // ---- S[zl][n][k] = 0.125 * Q[:,h*64:+64] @ EK[z]^T  (f16)
        GemmP ps{};
        ps.A = Qb + h0 * 64; ps.aLo = 64; ps.sAm = 1024; ps.K = 64;
        ps.B = EK + (size_t)(b * 16 + h0) * 16384; ps.bLo = 16384; ps.sBn = 64;
        ps.C = R; ps.cLo = 1048576; ps.sCm = 256; ps.sCn = 1;
        ps.scale = 0.125f; ps.cdtype = 2;
        gemm_nt<128,128,2,2><<<dim3(32, 2, zc), 256, 0, stream>>>(ps);

        softmax_kernel<<<zc * 1024, 256, 0, stream>>>((unsigned short*)R);

        // ---- attn -> cat (aliases Qb) cols [h0*64, (h0+zc)*64)
        GemmP pp{};
        pp.A = (unsigned short*)R; pp.aLo = 1048576; pp.sAm = 256; pp.K = 256;
        pp.B = EVt + (size_t)(b * 16 + h0) * 16384; pp.bLo = 16384; pp.sBn = 256;
        pp.C = Qb + h0 * 64; pp.cLo = 64; pp.sCm = 1024; pp.sCn = 1;
        pp.scale = 1.f; pp.cdtype = 0;
        gemm_nt<128,64,4,1><<<dim3(32, 1, zc), 256, 0, stream>>>(pp);
      }

      // ---- xf[b] += cat @ wo^T + wo_b   (f32 accumulate epilogue)
      GemmP pw{};
      pw.A = Qb; pw.sAm = 1024; pw.K = 1024;
      pw.B = WoL; pw.sBn = 1024;
      pw.biasN = wo_b + (size_t)l * 1024;
      pw.C = xf + (size_t)b * 4194304; pw.cdtype = 3;
      pw.sCm = 1024; pw.sCn = 1; pw.scale = 1.f;
      gemm_nt<128,128,2,2><<<dim3(32, 8, 1), 256, 0, stream>>>(pw);
    }
    add_ln_kernel<<<16384, 256, 0, stream>>>(xf, xd, ln1_g + (size_t)l * 1024,
                                             ln1_b + (size_t)l * 1024);

    // ---- FFN, row-chunked
    for (int r0 = 0; r0 < 16384; r0 += rowc) {
      GemmP f1{};
      f1.A = xd + (size_t)r0 * 1024; f1.sAm = 1024; f1.K = 1024;
      f1.B = F1L; f1.sBn = 1024;
      f1.C = R; f1.sCm = 4096; f1.sCn = 1;
      f1.biasN = ff_b1 + (size_t)l * 4096; f1.scale = 1.f; f1.relu = 1; f1.cdtype = 0;
      gemm_nt<128,128,2,2><<<dim3(rowc / 128, 32, 1), 256, 0, stream>>>(f1);

      GemmP f2{};
      f2.A = (unsigned short*)R; f2.sAm = 4096; f2.K = 4096;
      f2.B = F2L; f2.sBn = 4096;
      f2.biasN = ff_b2 + (size_t)l * 1024;
      f2.C = xf + (size_t)r0 * 1024; f2.cdtype = 3;
      f2.sCm = 1024; f2.sCn = 1; f2.scale = 1.f;
      gemm_nt<128,128,2,2><<<dim3(rowc / 128, 8, 1), 256, 0, stream>>>(f2);
    }
    add_ln_kernel<<<16384, 256, 0, stream>>>(xf, xd, ln2_g + (size_t)l * 1024,
                                             ln2_b + (size_t)l * 1024);
  }
}

// Round 5
// 1656.864 us; speedup vs baseline: 1.4241x; 1.4241x over previous
//
#include <hip/hip_runtime.h>
#include <hip/hip_bf16.h>
#include <hip/hip_fp16.h>

typedef __attribute__((ext_vector_type(8))) short short8;
typedef __attribute__((ext_vector_type(4))) float f32x4;

__device__ __forceinline__ unsigned short dev_f2bf(float f) {
  __hip_bfloat16 b = __float2bfloat16(f);
  union { __hip_bfloat16 b; unsigned short u; } c; c.b = b; return c.u;
}
__device__ __forceinline__ float dev_bf2f(unsigned short u) {
  union { unsigned int i; float f; } c; c.i = ((unsigned int)u) << 16; return c.f;
}
__device__ __forceinline__ unsigned short dev_f2h(float f) {
  __half h = __float2half(f);
  union { __half h; unsigned short u; } c; c.h = h; return c.u;
}
__device__ __forceinline__ float dev_h2f(unsigned short u) {
  union { unsigned short u; __half h; } c; c.u = u; return __half2float(c.h);
}

// async global->LDS, 16B per lane; dest = lds_base(wave-uniform) + lane*16
__device__ __forceinline__ void gload_lds16(const unsigned short* g, unsigned short* l) {
  __builtin_amdgcn_global_load_lds(
      (const __attribute__((address_space(1))) void*)(const void*)g,
      (__attribute__((address_space(3))) void*)(void*)l, 16, 0, 0);
}

struct GemmP {
  const unsigned short* A;   // bf16 bits
  const unsigned short* B;   // bf16 bits
  void* C;
  const float* biasN;        // bias by output col, may be null
  const float* biasM;        // bias by output row, may be null
  long long aHi, aLo, bHi, bLo, cHi, cLo;  // per-z base: (z>>4)*Hi + (z&15)*Lo
  int K;
  int sAm;                   // A row stride (k stride == 1)
  int sBn;                   // B row stride (k stride == 1)
  int sCm, sCn;
  float scale;
  int relu;
  int cdtype;                // 0=bf16, 1=f32, 2=f16, 3=f32 +=
};

// General NT GEMM: C[z,m,n] = scale * sum_k A[m,k]*B[n,k] + biases
// global_load_lds(16B) staging, linear LDS [rows][64 shorts], XOR-swizzled:
//   LDS(row, c16) holds global(row, c16 ^ (row&7))  [c16 = 16-byte column 0..7]
// Source permutation applied on the per-lane GLOBAL address; read applies same XOR.
template<int BM, int BN, int WM, int WN>
__global__ __launch_bounds__(256, 2) void gemm_nt(GemmP p) {
  constexpr int BK = 64;
  constexpr int TM = BM / WM, TN = BN / WN;
  constexpr int FM = TM / 16, FN = TN / 16;
  __shared__ __align__(16) unsigned short As[BM * BK];
  __shared__ __align__(16) unsigned short Bs[BN * BK];

  const int tid = threadIdx.x;
  const int lane = tid & 63;
  const int wid = tid >> 6;
  const int wm = wid / WN, wn = wid % WN;
  const int m0 = blockIdx.x * BM;
  const int n0 = blockIdx.y * BN;
  const int z = blockIdx.z;
  const int zq = z >> 4, zr = z & 15;
  const unsigned short* Ag = p.A + (long long)zq * p.aHi + (long long)zr * p.aLo;
  const unsigned short* Bg = p.B + (long long)zq * p.bHi + (long long)zr * p.bLo;

  const int srow = tid >> 3;                      // 0..31
  const int scol = ((tid & 7) ^ (srow & 7)) * 8;  // swizzled 16B column
  constexpr int AC = BM / 32, BC = BN / 32;

  f32x4 acc[FM][FN];
#pragma unroll
  for (int i = 0; i < FM; i++)
#pragma unroll
    for (int j = 0; j < FN; j++)
      acc[i][j] = f32x4{0.f, 0.f, 0.f, 0.f};

  for (int k0 = 0; k0 < p.K; k0 += BK) {
#pragma unroll
    for (int i = 0; i < AC; i++)
      gload_lds16(Ag + (long long)(m0 + i * 32 + srow) * p.sAm + (k0 + scol),
                  &As[i * 2048 + wid * 512]);
#pragma unroll
    for (int i = 0; i < BC; i++)
      gload_lds16(Bg + (long long)(n0 + i * 32 + srow) * p.sBn + (k0 + scol),
                  &Bs[i * 2048 + wid * 512]);
    __syncthreads();
#pragma unroll
    for (int ks = 0; ks < 2; ks++) {
      const int c16 = ks * 4 + (lane >> 4);
      short8 a[FM], b[FN];
#pragma unroll
      for (int i = 0; i < FM; i++) {
        const int row = wm * TM + i * 16 + (lane & 15);
        a[i] = *(const short8*)&As[row * 64 + (c16 ^ (row & 7)) * 8];
      }
#pragma unroll
      for (int j = 0; j < FN; j++) {
        const int row = wn * TN + j * 16 + (lane & 15);
        b[j] = *(const short8*)&Bs[row * 64 + (c16 ^ (row & 7)) * 8];
      }
#pragma unroll
      for (int i = 0; i < FM; i++)
#pragma unroll
        for (int j = 0; j < FN; j++)
          acc[i][j] = __builtin_amdgcn_mfma_f32_16x16x32_bf16(a[i], b[j], acc[i][j], 0, 0, 0);
    }
    __syncthreads();
  }

  const long long zc_ = (long long)zq * p.cHi + (long long)zr * p.cLo;
#pragma unroll
  for (int i = 0; i < FM; i++) {
#pragma unroll
    for (int j = 0; j < FN; j++) {
      const int col = n0 + wn * TN + j * 16 + (lane & 15);
      float bn = p.biasN ? p.biasN[col] : 0.f;
#pragma unroll
      for (int r = 0; r < 4; r++) {
        const int row = m0 + wm * TM + i * 16 + ((lane >> 4) << 2) + r;
        float v = acc[i][j][r] * p.scale + bn;
        if (p.biasM) v += p.biasM[row];
        if (p.relu) v = fmaxf(v, 0.f);
        const long long addr = zc_ + (long long)row * p.sCm + (long long)col * p.sCn;
        if (p.cdtype == 0)      ((unsigned short*)p.C)[addr] = dev_f2bf(v);
        else if (p.cdtype == 1) ((float*)p.C)[addr] = v;
        else if (p.cdtype == 2) ((unsigned short*)p.C)[addr] = dev_f2h(v);
        else                    ((float*)p.C)[addr] += v;
      }
    }
  }
}

// 64x64 tiled transpose: in [b][4096][1024] -> out [b][1024][4096] (bf16)
__global__ __launch_bounds__(256) void transpose_kernel(const unsigned short* __restrict__ in,
                                                        unsigned short* __restrict__ out) {
  __shared__ unsigned short t[64][72];
  const int b = blockIdx.z;
  const int n0 = blockIdx.x * 64, c0 = blockIdx.y * 64;
  const int r = threadIdx.x >> 2;          // 0..63
  const int cc = (threadIdx.x & 3) * 16;   // 0,16,32,48
  const unsigned short* ip = in + (size_t)b * 4194304 + (size_t)n0 * 1024 + c0;
  *(short8*)&t[r][cc]     = *(const short8*)(ip + (size_t)r * 1024 + cc);
  *(short8*)&t[r][cc + 8] = *(const short8*)(ip + (size_t)r * 1024 + cc + 8);
  __syncthreads();
  unsigned short* op = out + (size_t)b * 4194304 + (size_t)c0 * 4096 + n0;
  short8 w0, w1;
#pragma unroll
  for (int j = 0; j < 8; j++) {
    w0[j] = (short)t[cc + j][r];
    w1[j] = (short)t[cc + 8 + j][r];
  }
  *(short8*)(op + (size_t)r * 4096 + cc)     = w0;
  *(short8*)(op + (size_t)r * 4096 + cc + 8) = w1;
}

// f32 -> bf16 (optionally also copy raw f32), x4 vectorized, grid-stride
__global__ void cvt_kernel(const float* __restrict__ src, unsigned short* __restrict__ dst,
                           float* __restrict__ dstf, long long n4) {
  long long i = (long long)blockIdx.x * blockDim.x + threadIdx.x;
  const long long stride = (long long)gridDim.x * blockDim.x;
  for (; i < n4; i += stride) {
    float4 v = ((const float4*)src)[i];
    ushort4 u;
    u.x = dev_f2bf(v.x); u.y = dev_f2bf(v.y); u.z = dev_f2bf(v.z); u.w = dev_f2bf(v.w);
    ((ushort4*)dst)[i] = u;
    if (dstf) ((float4*)dstf)[i] = v;
  }
}

// rows of 256: f16 scores in, bf16 probs out, in place; one wave per row
__global__ __launch_bounds__(256) void softmax_kernel(unsigned short* __restrict__ S) {
  const long long row = (long long)blockIdx.x * 4 + (threadIdx.x >> 6);
  const int lane = threadIdx.x & 63;
  unsigned short* rp = S + row * 256;
  ushort4 u = *(const ushort4*)(rp + lane * 4);
  float x0 = dev_h2f(u.x), x1 = dev_h2f(u.y), x2 = dev_h2f(u.z), x3 = dev_h2f(u.w);
  float m = fmaxf(fmaxf(x0, x1), fmaxf(x2, x3));
#pragma unroll
  for (int off = 32; off > 0; off >>= 1) m = fmaxf(m, __shfl_xor(m, off));
  float e0 = __expf(x0 - m), e1 = __expf(x1 - m), e2 = __expf(x2 - m), e3 = __expf(x3 - m);
  float s = e0 + e1 + e2 + e3;
#pragma unroll
  for (int off = 32; off > 0; off >>= 1) s += __shfl_xor(s, off);
  const float inv = 1.f / s;
  ushort4 o;
  o.x = dev_f2bf(e0 * inv); o.y = dev_f2bf(e1 * inv);
  o.z = dev_f2bf(e2 * inv); o.w = dev_f2bf(e3 * inv);
  *(ushort4*)(rp + lane * 4) = o;
}

// LN over rows of 1024 of xf (f32, holds x+y). Writes LN result to xf and bf16 to xd.
__global__ __launch_bounds__(256) void add_ln_kernel(float* __restrict__ xf,
    unsigned short* __restrict__ xd,
    const float* __restrict__ g, const float* __restrict__ b) {
  const long long row = blockIdx.x;
  const int tid = threadIdx.x;
  float4 t = ((const float4*)(xf + row * 1024))[tid];
  float s = t.x + t.y + t.z + t.w;
  float ss = t.x * t.x + t.y * t.y + t.z * t.z + t.w * t.w;
#pragma unroll
  for (int off = 32; off > 0; off >>= 1) { s += __shfl_xor(s, off); ss += __shfl_xor(ss, off); }
  __shared__ float sm[8];
  const int wid = tid >> 6, lane = tid & 63;
  if (lane == 0) { sm[wid] = s; sm[4 + wid] = ss; }
  __syncthreads();
  s = sm[0] + sm[1] + sm[2] + sm[3];
  ss = sm[4] + sm[5] + sm[6] + sm[7];
  const float mean = s * (1.f / 1024.f);
  const float var = ss * (1.f / 1024.f) - mean * mean;
  const float rs = rsqrtf(var + 1e-5f);
  float4 gv = ((const float4*)g)[tid];
  float4 bv = ((const float4*)b)[tid];
  float4 o = {(t.x - mean) * rs * gv.x + bv.x, (t.y - mean) * rs * gv.y + bv.y,
              (t.z - mean) * rs * gv.z + bv.z, (t.w - mean) * rs * gv.w + bv.w};
  ((float4*)(xf + row * 1024))[tid] = o;
  ushort4 ob;
  ob.x = dev_f2bf(o.x); ob.y = dev_f2bf(o.y); ob.z = dev_f2bf(o.z); ob.w = dev_f2bf(o.w);
  ((ushort4*)(xd + row * 1024))[tid] = ob;
}

// canary: unambiguous "workspace too small" signal (absmax ~ 100+max|ref|)
__global__ void fill_canary_kernel(float* p, long long n) {
  long long i = (long long)blockIdx.x * blockDim.x + threadIdx.x;
  const long long stride = (long long)gridDim.x * blockDim.x;
  for (; i < n; i += stride) p[i] = 100.0f;
}

extern "C" void kernel_launch(void* const* d_in, const int* in_sizes, int n_in,
                              void* d_out, int out_size, void* d_ws, size_t ws_size,
                              hipStream_t stream) {
  const float* x_in  = (const float*)d_in[0];
  const float* E_w   = (const float*)d_in[1];
  const float* E_b   = (const float*)d_in[2];
  const float* Wq    = (const float*)d_in[3];
  const float* Wk    = (const float*)d_in[4];
  const float* Wv    = (const float*)d_in[5];
  const float* wo_w  = (const float*)d_in[6];
  const float* wo_b  = (const float*)d_in[7];
  const float* ln1_g = (const float*)d_in[8];
  const float* ln1_b = (const float*)d_in[9];
  const float* ff_w1 = (const float*)d_in[10];
  const float* ff_b1 = (const float*)d_in[11];
  const float* ff_w2 = (const float*)d_in[12];
  const float* ff_b2 = (const float*)d_in[13];
  const float* ln2_g = (const float*)d_in[14];
  const float* ln2_b = (const float*)d_in[15];

  float* xf = (float*)d_out;   // f32 residual master lives in d_out

  char* ws = (char*)d_ws;
  size_t off = 0;
  auto alloc = [&](size_t bytes) -> char* {
    char* p = ws + off;
    off = (off + bytes + 255) & ~(size_t)255;
    return p;
  };
  unsigned short* E16 = (unsigned short*)alloc(1048576ULL * 2);  // E_w bf16 [256,4096]
  unsigned short* WqL = (unsigned short*)alloc(1048576ULL * 2);  // per-layer slices
  unsigned short* WkL = (unsigned short*)alloc(1048576ULL * 2);
  unsigned short* WvL = (unsigned short*)alloc(1048576ULL * 2);
  unsigned short* WoL = (unsigned short*)alloc(1048576ULL * 2);
  unsigned short* F1L = (unsigned short*)alloc(4194304ULL * 2);
  unsigned short* F2L = (unsigned short*)alloc(4194304ULL * 2);
  unsigned short* xE  = (unsigned short*)alloc(1048576ULL * 2);  // [b][256][1024]
  unsigned short* EK  = (unsigned short*)alloc(1048576ULL * 2);  // [z][256][64]
  unsigned short* EVt = (unsigned short*)alloc(1048576ULL * 2);  // [z][64][256]
  unsigned short* xd  = (unsigned short*)alloc(16777216ULL * 2); // bf16 working x
  unsigned short* xT  = (unsigned short*)alloc(16777216ULL * 2); // x^T [b][1024][4096]; later Q/cat
  unsigned short* Qb4 = xT;   // alias: xT dead once pe is done; Q/cat [16384][1024]

  size_t rem = (ws_size > off) ? ws_size - off : 0;
  size_t Rbytes = rem > 512 ? rem - 512 : 0;
  if (Rbytes > 134217728ULL) Rbytes = 134217728ULL;
  int zc = 64;     // heads-chunk over z=0..63 (S chunk = zc * 2 MiB)
  while (zc > 1 && (size_t)zc * 2097152ULL > Rbytes) zc >>= 1;
  int rowc = 16384;
  while (rowc > 128 && (size_t)rowc * 8192ULL > Rbytes) rowc >>= 1;
  if ((size_t)zc * 2097152ULL > Rbytes || (size_t)rowc * 8192ULL > Rbytes) {
    fill_canary_kernel<<<2048, 256, 0, stream>>>(xf, (long long)out_size);
    return;
  }
  char* R = alloc(Rbytes);

  auto cvt = [&](const float* s, unsigned short* d, float* df, long long n) {
    long long n4 = n / 4;
    int grid = (int)((n4 + 255) / 256);
    if (grid > 4096) grid = 4096;
    cvt_kernel<<<grid, 256, 0, stream>>>(s, d, df, n4);
  };

  cvt(x_in, xd, xf, 16777216);     // x: bf16 into ws, f32 master into d_out
  cvt(E_w, E16, nullptr, 1048576);

  for (int l = 0; l < 2; l++) {
    cvt(Wq + (size_t)l * 1048576, WqL, nullptr, 1048576);
    cvt(Wk + (size_t)l * 1048576, WkL, nullptr, 1048576);
    cvt(Wv + (size_t)l * 1048576, WvL, nullptr, 1048576);
    cvt(wo_w + (size_t)l * 1048576, WoL, nullptr, 1048576);
    cvt(ff_w1 + (size_t)l * 4194304, F1L, nullptr, 4194304);
    cvt(ff_w2 + (size_t)l * 4194304, F2L, nullptr, 4194304);

    // ---- xT[b][c][n] = x[b][n][c]
    transpose_kernel<<<dim3(64, 16, 4), 256, 0, stream>>>(xd, xT);

    // ---- xE[b][k][c] = sum_n E_w[k,n] * xT[b][c][n]   (pure NT, z = b)
    GemmP pe{};
    pe.A = E16; pe.sAm = 4096; pe.K = 4096;
    pe.B = xT; pe.sBn = 4096; pe.bLo = 4194304;
    pe.C = xE; pe.cLo = 262144; pe.sCm = 1024; pe.sCn = 1;
    pe.scale = 1.f; pe.cdtype = 0;
    gemm_nt<64,128,2,2><<<dim3(4, 8, 4), 256, 0, stream>>>(pe);

    // ---- EK[z][k][d] = xE[b] @ Wk[h]^T + E_b[k]   (z = b*16+h)
    GemmP pk{};
    pk.A = xE; pk.sAm = 1024; pk.K = 1024; pk.aHi = 262144; pk.aLo = 0;
    pk.B = WkL; pk.sBn = 1024; pk.bHi = 0; pk.bLo = 65536;
    pk.C = EK; pk.cHi = 262144; pk.cLo = 16384; pk.sCm = 64; pk.sCn = 1;
    pk.biasM = E_b; pk.scale = 1.f; pk.cdtype = 0;
    gemm_nt<64,64,2,2><<<dim3(4, 1, 64), 256, 0, stream>>>(pk);
    // ---- EVt[z][d][k] = (xE[b] @ Wv[h]^T + E_b[k])^T
    GemmP pv2 = pk;
    pv2.B = WvL; pv2.C = EVt; pv2.sCm = 1; pv2.sCn = 256;
    gemm_nt<64,64,2,2><<<dim3(4, 1, 64), 256, 0, stream>>>(pv2);

    // ---- Q (all batches) = x @ Wq^T : [16384,1024]   (overwrites xT region)
    GemmP pq{};
    pq.A = xd; pq.sAm = 1024; pq.K = 1024;
    pq.B = WqL; pq.sBn = 1024;
    pq.C = Qb4; pq.sCm = 1024; pq.sCn = 1;
    pq.scale = 1.f; pq.cdtype = 0;
    gemm_nt<128,128,2,2><<<dim3(128, 8, 1), 256, 0, stream>>>(pq);

    for (int z0 = 0; z0 < 64; z0 += zc) {
      const long long aOff = (long long)(z0 >> 4) * 4194304 + (long long)(z0 & 15) * 64;
      const long long eOff = (long long)z0 * 16384;
      // ---- S[zl][n][k] = 0.125 * Q[b, :, h*64:+64] @ EK[z]^T  (f16)
      GemmP ps{};
      ps.A = Qb4 + aOff; ps.aHi = 4194304; ps.aLo = 64; ps.sAm = 1024; ps.K = 64;
      ps.B = EK + eOff; ps.bHi = 262144; ps.bLo = 16384; ps.sBn = 64;
      ps.C = R; ps.cHi = 16777216; ps.cLo = 1048576; ps.sCm = 256; ps.sCn = 1;
      ps.scale = 0.125f; ps.cdtype = 2;
      gemm_nt<128,128,2,2><<<dim3(32, 2, zc), 256, 0, stream>>>(ps);

      softmax_kernel<<<zc * 1024, 256, 0, stream>>>((unsigned short*)R);

      // ---- attn = P @ EVt^T -> cat[b][n][h*64+d]  (cat aliases Qb4; per-z col slice)
      GemmP pp{};
      pp.A = (unsigned short*)R; pp.aHi = 16777216; pp.aLo = 1048576; pp.sAm = 256; pp.K = 256;
      pp.B = EVt + eOff; pp.bHi = 262144; pp.bLo = 16384; pp.sBn = 256;
      pp.C = Qb4 + aOff; pp.cHi = 4194304; pp.cLo = 64; pp.sCm = 1024; pp.sCn = 1;
      pp.scale = 1.f; pp.cdtype = 0;
      gemm_nt<128,64,4,1><<<dim3(32, 1, zc), 256, 0, stream>>>(pp);
    }

    // ---- xf += cat @ wo^T + wo_b   (f32 accumulate epilogue, all batches)
    GemmP pw{};
    pw.A = Qb4; pw.sAm = 1024; pw.K = 1024;
    pw.B = WoL; pw.sBn = 1024;
    pw.biasN = wo_b + (size_t)l * 1024;
    pw.C = xf; pw.cdtype = 3;
    pw.sCm = 1024; pw.sCn = 1; pw.scale = 1.f;
    gemm_nt<128,128,2,2><<<dim3(128, 8, 1), 256, 0, stream>>>(pw);

    add_ln_kernel<<<16384, 256, 0, stream>>>(xf, xd, ln1_g + (size_t)l * 1024,
                                             ln1_b + (size_t)l * 1024);

    // ---- FFN, row-chunked
    for (int r0 = 0; r0 < 16384; r0 += rowc) {
      GemmP f1{};
      f1.A = xd + (size_t)r0 * 1024; f1.sAm = 1024; f1.K = 1024;
      f1.B = F1L; f1.sBn = 1024;
      f1.C = R; f1.sCm = 4096; f1.sCn = 1;
      f1.biasN = ff_b1 + (size_t)l * 4096; f1.scale = 1.f; f1.relu = 1; f1.cdtype = 0;
      gemm_nt<128,128,2,2><<<dim3(rowc / 128, 32, 1), 256, 0, stream>>>(f1);

      GemmP f2{};
      f2.A = (unsigned short*)R; f2.sAm = 4096; f2.K = 4096;
      f2.B = F2L; f2.sBn = 4096;
      f2.biasN = ff_b2 + (size_t)l * 1024;
      f2.C = xf + (size_t)r0 * 1024; f2.cdtype = 3;
      f2.sCm = 1024; f2.sCn = 1; f2.scale = 1.f;
      gemm_nt<128,128,2,2><<<dim3(rowc / 128, 8, 1), 256, 0, stream>>>(f2);
    }
    add_ln_kernel<<<16384, 256, 0, stream>>>(xf, xd, ln2_g + (size_t)l * 1024,
                                             ln2_b + (size_t)l * 1024);
  }
}